// Round 1
// baseline (1705.001 us; speedup 1.0000x reference)
//
#include <hip/hip_runtime.h>
#include <cstdint>
#include <cstddef>

// ---------------------------------------------------------------------------
// WindowAttention (Swin-style) on MI355X / gfx950.
//   B=2048 windows, N=64 tokens, DIM=512, HEADS=16, HEAD_DIM=32, NW=64 masks.
// Pipeline:
//   prep:  q -> bf16 ; [q_w*SCALE ; kv_w] -> bf16 B^T (1536x512); proj_w -> bf16;
//          bias_table[rel_index] -> biasF[16][64][64]; fused bias vector bc.
//   gemm1: QKV[m][1536] = q @ Wc^T + bc      (bf16 MFMA, m97-style tile)
//   attn:  per (b,h) wave: S=QK^T (MFMA) + bias + mask, softmax (in-regs),
//          attn -> d_out fp32, P@V (MFMA) -> xh bf16
//   gemm3: x = xh @ proj_w^T + proj_b -> d_out fp32
// Workspace: 539,236,352 bytes (xh aliases the q-bf16 buffer; safe: sequential).
// ---------------------------------------------------------------------------

typedef __bf16 bf16x8 __attribute__((ext_vector_type(8)));
typedef float  f32x4  __attribute__((ext_vector_type(4)));

#define MFMA16(a, b, c) __builtin_amdgcn_mfma_f32_16x16x32_bf16(a, b, c, 0, 0, 0)

__device__ __forceinline__ unsigned short f2bf(float f) {
  unsigned u = __float_as_uint(f);
  u += 0x7fffu + ((u >> 16) & 1u);   // round-to-nearest-even
  return (unsigned short)(u >> 16);
}

// async global->LDS, 16B per lane (global_load_lds_dwordx4)
__device__ __forceinline__ void gl2lds16(const void* g, void* l) {
  __builtin_amdgcn_global_load_lds(
      (const __attribute__((address_space(1))) void*)g,
      (__attribute__((address_space(3))) void*)l, 16, 0, 0);
}

// ---------------------------------------------------------------------------
// prep kernels
// ---------------------------------------------------------------------------

// cast q (131072x512 fp32) -> bf16, 8 elems/thread, grid exactly covers
__global__ __launch_bounds__(256) void cast_q_k(const float* __restrict__ src,
                                                unsigned short* __restrict__ dst) {
  long idx = (long)blockIdx.x * 256 + threadIdx.x;  // chunk of 8
  const float4* p = (const float4*)(src + idx * 8);
  float4 a = p[0], b = p[1];
  ushort4 r0 = make_ushort4(f2bf(a.x), f2bf(a.y), f2bf(a.z), f2bf(a.w));
  ushort4 r1 = make_ushort4(f2bf(b.x), f2bf(b.y), f2bf(b.z), f2bf(b.w));
  ushort4* o = (ushort4*)(dst + idx * 8);
  o[0] = r0; o[1] = r1;
}

// pack Wc (rows 0..511 = q_w*SCALE, 512..1535 = kv_w) and proj_w, both bf16.
// chunk ids: [0,98304) -> Wc ; [98304,131072) -> pw. grid 512x256 exact.
__global__ __launch_bounds__(256) void pack_w_k(const float* __restrict__ qw,
                                                const float* __restrict__ kvw,
                                                const float* __restrict__ pwsrc,
                                                unsigned short* __restrict__ Wc,
                                                unsigned short* __restrict__ pw,
                                                float scale) {
  int idx = blockIdx.x * 256 + threadIdx.x;
  const float* src;
  unsigned short* dst;
  float s = 1.0f;
  if (idx < 98304) {
    long e = (long)idx * 8;
    int row = (int)(e >> 9);
    int k = (int)(e & 511);
    if (row < 512) { src = qw + (long)row * 512 + k; s = scale; }
    else           { src = kvw + (long)(row - 512) * 512 + k; }
    dst = Wc + e;
  } else {
    long e = (long)(idx - 98304) * 8;
    src = pwsrc + e;
    dst = pw + e;
  }
  float4 a = ((const float4*)src)[0];
  float4 b = ((const float4*)src)[1];
  ushort4 r0 = make_ushort4(f2bf(a.x * s), f2bf(a.y * s), f2bf(a.z * s), f2bf(a.w * s));
  ushort4 r1 = make_ushort4(f2bf(b.x * s), f2bf(b.y * s), f2bf(b.z * s), f2bf(b.w * s));
  ((ushort4*)dst)[0] = r0;
  ((ushort4*)dst)[1] = r1;
}

// biasF[h][i][j] = bias_table[rel[i*64+j]*16+h]  (idx < 65536)
// bc[i] = i<512 ? q_b[i]*scale : kv_b[i-512]     (idx in [65536, 67072))
// grid 262x256 = 67072 exact.
__global__ __launch_bounds__(256) void prep_misc_k(const float* __restrict__ btab,
                                                   const int* __restrict__ rel,
                                                   const float* __restrict__ qb,
                                                   const float* __restrict__ kvb,
                                                   float* __restrict__ biasF,
                                                   float* __restrict__ bc,
                                                   float scale) {
  int idx = blockIdx.x * 256 + threadIdx.x;
  if (idx < 65536) {
    int ij = idx & 4095;
    int h = idx >> 12;
    biasF[idx] = btab[rel[ij] * 16 + h];
  } else {
    int i = idx - 65536;
    bc[i] = (i < 512) ? qb[i] * scale : kvb[i - 512];
  }
}

// ---------------------------------------------------------------------------
// bf16 B^T GEMM: C[m][n] = sum_k A[m][k]*B[n][k] + bias[n]
// A: M x 512 bf16, B: N x 512 bf16. Tile 128x128, BK=64, 4 waves (2x2),
// each wave 4x4 MFMA 16x16x32. global_load_lds w=16, XOR chunk swizzle.
// ---------------------------------------------------------------------------
template <bool BF16OUT>
__global__ __launch_bounds__(256) void gemm_bt(const unsigned short* __restrict__ A,
                                               const unsigned short* __restrict__ B,
                                               const float* __restrict__ bias,
                                               void* __restrict__ Cp, int N) {
  __shared__ unsigned short As[128 * 64];
  __shared__ unsigned short Bs[128 * 64];
  const int t = threadIdx.x;
  const int lane = t & 63;
  const int wave = t >> 6;
  const int wm = wave >> 1, wn = wave & 1;
  const int quad = lane >> 4, col = lane & 15;
  const long m0 = (long)blockIdx.x * 128;
  const long n0 = (long)blockIdx.y * 128;

  // staging: 1024 16B-chunks per tile, 4 per thread. LDS chunk cl of row r
  // holds global chunk cl^(r&7)  (bank-conflict-free fragment reads).
  int sidx[4];
  long ga[4], gb[4];
#pragma unroll
  for (int i = 0; i < 4; ++i) {
    int idx = i * 256 + t;
    int r = idx >> 3, cl = idx & 7;
    int cg = cl ^ (r & 7);
    sidx[i] = idx * 8;
    ga[i] = (m0 + r) * 512 + cg * 8;
    gb[i] = (n0 + r) * 512 + cg * 8;
  }

  // fragment LDS offsets (elements) per k-step
  int offA[2][4], offB[2][4];
#pragma unroll
  for (int mt = 0; mt < 4; ++mt) {
    int rA = wm * 64 + mt * 16 + col;
    int rB = wn * 64 + mt * 16 + col;
#pragma unroll
    for (int ks = 0; ks < 2; ++ks) {
      offA[ks][mt] = rA * 64 + (((ks * 4 + quad) ^ (rA & 7)) * 8);
      offB[ks][mt] = rB * 64 + (((ks * 4 + quad) ^ (rB & 7)) * 8);
    }
  }

  f32x4 acc[4][4];
#pragma unroll
  for (int i = 0; i < 4; ++i)
#pragma unroll
    for (int j = 0; j < 4; ++j) acc[i][j] = (f32x4){0.f, 0.f, 0.f, 0.f};

  for (int kt = 0; kt < 8; ++kt) {
    const unsigned short* Ak = A + kt * 64;
    const unsigned short* Bk = B + kt * 64;
#pragma unroll
    for (int i = 0; i < 4; ++i) gl2lds16(Ak + ga[i], &As[sidx[i]]);
#pragma unroll
    for (int i = 0; i < 4; ++i) gl2lds16(Bk + gb[i], &Bs[sidx[i]]);
    asm volatile("s_waitcnt vmcnt(0)" ::: "memory");
    __syncthreads();
#pragma unroll
    for (int ks = 0; ks < 2; ++ks) {
      bf16x8 af[4], bf[4];
#pragma unroll
      for (int mt = 0; mt < 4; ++mt) af[mt] = *(const bf16x8*)&As[offA[ks][mt]];
#pragma unroll
      for (int nt = 0; nt < 4; ++nt) bf[nt] = *(const bf16x8*)&Bs[offB[ks][nt]];
#pragma unroll
      for (int mt = 0; mt < 4; ++mt)
#pragma unroll
        for (int nt = 0; nt < 4; ++nt)
          acc[mt][nt] = MFMA16(af[mt], bf[nt], acc[mt][nt]);
    }
    __syncthreads();
  }

  // epilogue: C/D layout col=lane&15, row=quad*4+reg
#pragma unroll
  for (int nt = 0; nt < 4; ++nt) {
    long n = n0 + wn * 64 + nt * 16 + col;
    float bv = bias[n];
#pragma unroll
    for (int mt = 0; mt < 4; ++mt) {
      long mbase = m0 + wm * 64 + mt * 16 + quad * 4;
#pragma unroll
      for (int r = 0; r < 4; ++r) {
        float v = acc[mt][nt][r] + bv;
        long off = (mbase + r) * N + n;
        if (BF16OUT) ((unsigned short*)Cp)[off] = f2bf(v);
        else         ((float*)Cp)[off] = v;
      }
    }
  }
}

// ---------------------------------------------------------------------------
// attention: one 64-lane wave per (b,h).
// QKV layout: [m=b*64+n][o], o: 0..511 q*SCALE, 512..1023 k, 1024..1535 v,
// with head columns h*32+d inside each group.
// ---------------------------------------------------------------------------
__global__ __launch_bounds__(64) void attn_k(const unsigned short* __restrict__ QKV,
                                             const float* __restrict__ mask,
                                             const float* __restrict__ biasF,
                                             float* __restrict__ attn_out,
                                             unsigned short* __restrict__ xh) {
  __shared__ unsigned short Plds[64 * 72];  // P bf16, stride 72 (16B-aligned rows)
  __shared__ unsigned short Vt[32 * 72];    // V^T bf16 [d][j]
  const int bh = blockIdx.x;
  const int b = bh >> 4, h = bh & 15;
  const int lane = threadIdx.x;
  const int quad = lane >> 4, col = lane & 15;
  const unsigned short* base = QKV + (long)b * 64 * 1536 + h * 32;

  // transpose V (64x32) into Vt[d][j]; lane owns row j=lane
  {
    const unsigned short* vrow = base + 1024 + (long)lane * 1536;
#pragma unroll
    for (int c = 0; c < 4; ++c) {
      uint4 v = *(const uint4*)(vrow + c * 8);
      unsigned short* p = &Vt[(c * 8) * 72 + lane];
      p[0 * 72] = (unsigned short)(v.x);
      p[1 * 72] = (unsigned short)(v.x >> 16);
      p[2 * 72] = (unsigned short)(v.y);
      p[3 * 72] = (unsigned short)(v.y >> 16);
      p[4 * 72] = (unsigned short)(v.z);
      p[5 * 72] = (unsigned short)(v.z >> 16);
      p[6 * 72] = (unsigned short)(v.w);
      p[7 * 72] = (unsigned short)(v.w >> 16);
    }
  }

  // S = (Q*SCALE) K^T via MFMA; A/B frags straight from global (16B/lane)
  bf16x8 qf[4], kf[4];
#pragma unroll
  for (int mt = 0; mt < 4; ++mt)
    qf[mt] = *(const bf16x8*)(base + (long)(mt * 16 + col) * 1536 + quad * 8);
#pragma unroll
  for (int nt = 0; nt < 4; ++nt)
    kf[nt] = *(const bf16x8*)(base + 512 + (long)(nt * 16 + col) * 1536 + quad * 8);

  const f32x4 z = (f32x4){0.f, 0.f, 0.f, 0.f};
  f32x4 s[4][4];
#pragma unroll
  for (int mt = 0; mt < 4; ++mt)
#pragma unroll
    for (int nt = 0; nt < 4; ++nt)
      s[mt][nt] = MFMA16(qf[mt], kf[nt], z);

  // + bias + mask
  const float* mrow = mask + (long)(b & 63) * 4096;
  const float* brow = biasF + (long)h * 4096;
#pragma unroll
  for (int mt = 0; mt < 4; ++mt)
#pragma unroll
    for (int r = 0; r < 4; ++r) {
      int i = mt * 16 + quad * 4 + r;
#pragma unroll
      for (int nt = 0; nt < 4; ++nt) {
        int j = nt * 16 + col;
        s[mt][nt][r] += mrow[i * 64 + j] + brow[i * 64 + j];
      }
    }

  // softmax per row: row lives across lane&15 (x4 nt) at fixed quad
  float inv[4][4];
#pragma unroll
  for (int mt = 0; mt < 4; ++mt)
#pragma unroll
    for (int r = 0; r < 4; ++r) {
      float m = fmaxf(fmaxf(s[mt][0][r], s[mt][1][r]), fmaxf(s[mt][2][r], s[mt][3][r]));
      m = fmaxf(m, __shfl_xor(m, 1));
      m = fmaxf(m, __shfl_xor(m, 2));
      m = fmaxf(m, __shfl_xor(m, 4));
      m = fmaxf(m, __shfl_xor(m, 8));
      float sum = 0.f;
#pragma unroll
      for (int nt = 0; nt < 4; ++nt) {
        float p = __expf(s[mt][nt][r] - m);
        s[mt][nt][r] = p;
        sum += p;
      }
      sum += __shfl_xor(sum, 1);
      sum += __shfl_xor(sum, 2);
      sum += __shfl_xor(sum, 4);
      sum += __shfl_xor(sum, 8);
      inv[mt][r] = 1.0f / sum;
    }

  // write attn (fp32, required output) + P bf16 to LDS
  float* aout = attn_out + (long)bh * 4096;
#pragma unroll
  for (int mt = 0; mt < 4; ++mt)
#pragma unroll
    for (int r = 0; r < 4; ++r) {
      int i = mt * 16 + quad * 4 + r;
      float iv = inv[mt][r];
#pragma unroll
      for (int nt = 0; nt < 4; ++nt) {
        int j = nt * 16 + col;
        float p = s[mt][nt][r] * iv;
        aout[i * 64 + j] = p;
        Plds[i * 72 + j] = f2bf(p);
      }
    }
  __syncthreads();

  // O = P V  (A = P rows, B = Vt rows)
  f32x4 o[4][2];
#pragma unroll
  for (int mt = 0; mt < 4; ++mt)
#pragma unroll
    for (int n2 = 0; n2 < 2; ++n2) o[mt][n2] = z;
#pragma unroll
  for (int ks = 0; ks < 2; ++ks) {
    bf16x8 pa[4], vb[2];
#pragma unroll
    for (int mt = 0; mt < 4; ++mt)
      pa[mt] = *(const bf16x8*)&Plds[(mt * 16 + col) * 72 + ks * 32 + quad * 8];
#pragma unroll
    for (int n2 = 0; n2 < 2; ++n2)
      vb[n2] = *(const bf16x8*)&Vt[(n2 * 16 + col) * 72 + ks * 32 + quad * 8];
#pragma unroll
    for (int mt = 0; mt < 4; ++mt)
#pragma unroll
      for (int n2 = 0; n2 < 2; ++n2)
        o[mt][n2] = MFMA16(pa[mt], vb[n2], o[mt][n2]);
  }

  // xh[m=b*64+i][h*32+d] bf16
  unsigned short* xrow = xh + (long)b * 64 * 512 + h * 32;
#pragma unroll
  for (int mt = 0; mt < 4; ++mt)
#pragma unroll
    for (int n2 = 0; n2 < 2; ++n2)
#pragma unroll
      for (int r = 0; r < 4; ++r) {
        int i = mt * 16 + quad * 4 + r;
        int d = n2 * 16 + col;
        xrow[(long)i * 512 + d] = f2bf(o[mt][n2][r]);
      }
}

// ---------------------------------------------------------------------------
extern "C" void kernel_launch(void* const* d_in, const int* in_sizes, int n_in,
                              void* d_out, int out_size, void* d_ws, size_t ws_size,
                              hipStream_t stream) {
  const float* q      = (const float*)d_in[0];
  const float* mask   = (const float*)d_in[1];
  const float* q_w    = (const float*)d_in[2];
  const float* q_b    = (const float*)d_in[3];
  const float* kv_w   = (const float*)d_in[4];
  const float* kv_b   = (const float*)d_in[5];
  const float* proj_w = (const float*)d_in[6];
  const float* proj_b = (const float*)d_in[7];
  const float* btab   = (const float*)d_in[8];
  const int*   rel    = (const int*)d_in[9];

  char* ws = (char*)d_ws;
  unsigned short* Aq    = (unsigned short*)ws;                       // 134,217,728 B
  unsigned short* QKV   = (unsigned short*)(ws + 134217728LL);       // 402,653,184 B
  unsigned short* Wc    = (unsigned short*)(ws + 536870912LL);       //   1,572,864 B
  float*          bc    = (float*)(ws + 538443776LL);                //       6,144 B
  unsigned short* pw    = (unsigned short*)(ws + 538449920LL);       //     524,288 B
  float*          biasF = (float*)(ws + 538974208LL);                //     262,144 B
  unsigned short* xh    = Aq;  // alias: Aq dead after gemm1, xh written after

  float* x_out = (float*)d_out;
  float* attn_out = x_out + 67108864LL;  // x: 2048*64*512, attn: 2048*16*64*64

  const float scale = 0.17677669529663687f;  // HEAD_DIM^-0.5

  cast_q_k<<<32768, 256, 0, stream>>>(q, Aq);
  pack_w_k<<<512, 256, 0, stream>>>(q_w, kv_w, proj_w, Wc, pw, scale);
  prep_misc_k<<<262, 256, 0, stream>>>(btab, rel, q_b, kv_b, biasF, bc, scale);
  gemm_bt<true><<<dim3(1024, 12), 256, 0, stream>>>(Aq, Wc, bc, (void*)QKV, 1536);
  attn_k<<<32768, 64, 0, stream>>>(QKV, mask, biasF, attn_out, xh);
  gemm_bt<false><<<dim3(1024, 4), 256, 0, stream>>>(xh, pw, proj_b, (void*)x_out, 512);
}